// Round 10
// baseline (409.036 us; speedup 1.0000x reference)
//
#include <hip/hip_runtime.h>
#include <hip/hip_bf16.h>

// ---------------------------------------------------------------------------
// RewardGNN: 2-layer GCN (256->128->64) + mean-pool + linear head.
// Round 10:
//   - fuse deg_count (atomic-bound) with gemm1 (MFMA-bound): independent work,
//     interleaved block roles -> they co-schedule instead of serializing
//   - h1 stored bf16: gather<128> writes bf16 (51->12.8 MB), gemm2 reads bf16
//     A directly (no hi/lo split, 2 mfmas)
// CSR build: one u64 atomic per edge. Two-stage mean-pool.
// ---------------------------------------------------------------------------

static inline int ceil_div_ll(long long a, int b) { return (int)((a + b - 1) / b); }

typedef __attribute__((ext_vector_type(8))) short bf16x8;
typedef __attribute__((ext_vector_type(4))) float f32x4;

#define FIX_SCALE 33554432.0f   // 2^25

__device__ inline unsigned short f2bf(float f) {
    __hip_bfloat16 h = __float2bfloat16(f);  // round-to-nearest-even
    return *reinterpret_cast<unsigned short*>(&h);
}
__device__ inline float bf2f(unsigned short u) {
    unsigned int x = ((unsigned int)u) << 16;
    return __uint_as_float(x);
}

// pk[i] = count<<32 | deg_fixed ; init deg=1.0 (self-loop), count=0
__global__ void k_init_pk(unsigned long long* __restrict__ pk, int n) {
    int i = blockIdx.x * blockDim.x + threadIdx.x;
    if (i < n) pk[i] = (unsigned long long)(1u << 25);
}

// dinv[i] = rsqrt(deg), count[i] = in-count
__global__ void k_finish(const unsigned long long* __restrict__ pk, float* __restrict__ dinv,
                         int* __restrict__ count, int n) {
    int i = blockIdx.x * blockDim.x + threadIdx.x;
    if (i < n) {
        unsigned long long v = pk[i];
        float deg = (float)(unsigned int)(v & 0xffffffffull) * (1.0f / FIX_SCALE);
        dinv[i] = (deg > 0.f) ? rsqrtf(deg) : 0.f;
        count[i] = (int)(v >> 32);
    }
}

// ------------------------- 3-phase parallel scan ---------------------------
constexpr int SC_T = 256;
constexpr int SC_PER = 16;
constexpr int SC_CHUNK = SC_T * SC_PER;

__global__ void k_scan_a(const int* __restrict__ count, int* __restrict__ bsum, int n) {
    __shared__ int lds[SC_T];
    int b = blockIdx.x, t = threadIdx.x;
    int base = b * SC_CHUNK + t * SC_PER;
    int s = 0;
#pragma unroll
    for (int k = 0; k < SC_PER; ++k) {
        int idx = base + k;
        if (idx < n) s += count[idx];
    }
    lds[t] = s;
    __syncthreads();
    for (int off = 128; off > 0; off >>= 1) {
        if (t < off) lds[t] += lds[t + off];
        __syncthreads();
    }
    if (t == 0) bsum[b] = lds[0];
}

__global__ void k_scan_b(int* __restrict__ bsum, int nb) {
    if (threadIdx.x == 0) {
        int run = 0;
        for (int i = 0; i < nb; ++i) { int c = bsum[i]; bsum[i] = run; run += c; }
    }
}

__global__ void k_scan_c(const int* __restrict__ count, int* __restrict__ rowptr,
                         const int* __restrict__ bsum, int n) {
    __shared__ int lds[SC_T];
    int b = blockIdx.x, t = threadIdx.x;
    int base = b * SC_CHUNK + t * SC_PER;
    int v[SC_PER];
    int s = 0;
#pragma unroll
    for (int k = 0; k < SC_PER; ++k) {
        int idx = base + k;
        v[k] = (idx < n) ? count[idx] : 0;
        s += v[k];
    }
    lds[t] = s;
    for (int off = 1; off < SC_T; off <<= 1) {
        __syncthreads();
        int tmp = (t >= off) ? lds[t - off] : 0;
        __syncthreads();
        lds[t] += tmp;
    }
    __syncthreads();
    int run = bsum[b] + lds[t] - s;
#pragma unroll
    for (int k = 0; k < SC_PER; ++k) {
        int idx = base + k;
        if (idx < n) {
            rowptr[idx] = run;
            run += v[k];
            if (idx == n - 1) rowptr[n] = run;
        }
    }
}

// Fill CSR without atomics: pos = rowptr[dst] + slot[e]; one int2 store.
__global__ void k_csr_fill(const int* __restrict__ src, const int* __restrict__ dst,
                           const float* __restrict__ ew, const float* __restrict__ dinv,
                           const int* __restrict__ rowptr, const int* __restrict__ slot,
                           int2* __restrict__ csr, int E) {
    int e = blockIdx.x * blockDim.x + threadIdx.x;
    if (e < E) {
        int s = src[e], d = dst[e];
        int pos = rowptr[d] + slot[e];
        float coef = dinv[s] * ew[e] * dinv[d];
        csr[pos] = make_int2(s, __float_as_int(coef));
    }
}

// ---------------------------------------------------------------------------
// W pre-pack into MFMA B-fragment layout (hi/lo bf16).
// ---------------------------------------------------------------------------
template <int KDIM, int ODIM>
__global__ void k_wpack(const float* __restrict__ W, unsigned short* __restrict__ wpk) {
    constexpr int NKS = KDIM / 32, NF = ODIM / 16;
    int t = blockIdx.x * blockDim.x + threadIdx.x;
    if (t >= NKS * NF * 64) return;
    int lane = t & 63;
    int nf   = (t >> 6) % NF;
    int ks   = t / (64 * NF);
    int col  = nf * 16 + (lane & 15);
    int kb   = ks * 32 + (lane >> 4) * 8;
    bf16x8 hi, lo;
#pragma unroll
    for (int i = 0; i < 8; ++i) {
        float w = W[(size_t)(kb + i) * ODIM + col];
        unsigned short h = f2bf(w);
        hi[i] = (short)h;
        lo[i] = (short)f2bf(w - bf2f(h));
    }
    size_t base = (size_t)t * 8;
    *(bf16x8*)(wpk + base) = hi;
    *(bf16x8*)(wpk + (size_t)KDIM * ODIM + base) = lo;
}

// ---------------------------------------------------------------------------
// GEMM body (f32 A, split-precision, bf16 out) as a device function.
// ---------------------------------------------------------------------------
template <int KDIM, int ODIM>
__device__ __forceinline__ void gemm_f32A_body(const float* __restrict__ X,
                                               const unsigned short* __restrict__ wpk,
                                               unsigned short* __restrict__ Y, int n, int gb) {
    constexpr int NKS = KDIM / 32, NF = ODIM / 16;
    int wid  = threadIdx.x >> 6;
    int lane = threadIdx.x & 63;
    int rowbase = gb * 64 + wid * 16;
    int arow = rowbase + (lane & 15);
    int kb0  = (lane >> 4) * 8;
    const unsigned short* wlo = wpk + (size_t)KDIM * ODIM;
    bool aok = (arow < n);
    const float* xr = X + (size_t)arow * KDIM + kb0;

    f32x4 acc[NF];
#pragma unroll
    for (int f = 0; f < NF; ++f) acc[f] = (f32x4){0.f, 0.f, 0.f, 0.f};

#pragma unroll
    for (int ks = 0; ks < NKS; ++ks) {
        f32x4 a0 = (f32x4){0.f, 0.f, 0.f, 0.f};
        f32x4 a1 = (f32x4){0.f, 0.f, 0.f, 0.f};
        if (aok) {
            a0 = *(const f32x4*)(xr + ks * 32);
            a1 = *(const f32x4*)(xr + ks * 32 + 4);
        }
        bf16x8 ahi, alo;
#pragma unroll
        for (int i = 0; i < 4; ++i) {
            unsigned short h0 = f2bf(a0[i]);
            ahi[i]     = (short)h0;
            alo[i]     = (short)f2bf(a0[i] - bf2f(h0));
            unsigned short h1 = f2bf(a1[i]);
            ahi[i + 4] = (short)h1;
            alo[i + 4] = (short)f2bf(a1[i] - bf2f(h1));
        }
#pragma unroll
        for (int f = 0; f < NF; ++f) {
            size_t fb = (((size_t)ks * NF + f) * 64 + lane) * 8;
            bf16x8 bhi = *(const bf16x8*)(wpk + fb);
            bf16x8 blo = *(const bf16x8*)(wlo + fb);
            acc[f] = __builtin_amdgcn_mfma_f32_16x16x32_bf16(ahi, bhi, acc[f], 0, 0, 0);
            acc[f] = __builtin_amdgcn_mfma_f32_16x16x32_bf16(alo, bhi, acc[f], 0, 0, 0);
            acc[f] = __builtin_amdgcn_mfma_f32_16x16x32_bf16(ahi, blo, acc[f], 0, 0, 0);
        }
    }

    int r0  = rowbase + (lane >> 4) * 4;
    int col = lane & 15;
#pragma unroll
    for (int f = 0; f < NF; ++f) {
#pragma unroll
        for (int i = 0; i < 4; ++i) {
            int r = r0 + i;
            if (r < n) Y[(size_t)r * ODIM + f * 16 + col] = f2bf(acc[f][i]);
        }
    }
}

// ---------------------------------------------------------------------------
// Fused: deg_count (atomic-bound) + gemm1 (MFMA-bound), independent work.
// Every STRIDE-th block is a gemm block so both phases start immediately.
// ---------------------------------------------------------------------------
__global__ void k_deg_gemm1(const int* __restrict__ dst, const float* __restrict__ ew,
                            unsigned long long* __restrict__ pk, int* __restrict__ slot, int E,
                            const float* __restrict__ X, const unsigned short* __restrict__ wpk,
                            unsigned short* __restrict__ Y, int n,
                            int gemmBlocks, int stride) {
    int bid = blockIdx.x;
    int q = bid / stride;
    bool isGemm = (bid % stride == 0) && (q < gemmBlocks);
    if (isGemm) {
        gemm_f32A_body<256, 128>(X, wpk, Y, n, q);
    } else {
        int nGemmBefore = min(q + 1, gemmBlocks);  // gemm blocks among [0, bid]
        int db = bid - nGemmBefore;
        int e = db * 256 + (int)threadIdx.x;
        if (e < E) {
            unsigned int fx = __float2uint_rn(ew[e] * FIX_SCALE);
            unsigned long long old =
                atomicAdd(&pk[dst[e]], (1ull << 32) | (unsigned long long)fx);
            slot[e] = (int)(old >> 32);
        }
    }
}

// ---------------------------------------------------------------------------
// GEMM2: bf16 A (h1 stored bf16 -> exact fragment, no split), B hi/lo.
// ---------------------------------------------------------------------------
template <int KDIM, int ODIM>
__global__ void k_gemm_mfma_bfA(const unsigned short* __restrict__ X,
                                const unsigned short* __restrict__ wpk,
                                unsigned short* __restrict__ Y, int n) {
    constexpr int NKS = KDIM / 32, NF = ODIM / 16;
    int wid  = threadIdx.x >> 6;
    int lane = threadIdx.x & 63;
    int rowbase = blockIdx.x * 64 + wid * 16;
    int arow = rowbase + (lane & 15);
    int kb0  = (lane >> 4) * 8;
    const unsigned short* wlo = wpk + (size_t)KDIM * ODIM;
    bool aok = (arow < n);
    const unsigned short* xr = X + (size_t)arow * KDIM + kb0;

    f32x4 acc[NF];
#pragma unroll
    for (int f = 0; f < NF; ++f) acc[f] = (f32x4){0.f, 0.f, 0.f, 0.f};

#pragma unroll
    for (int ks = 0; ks < NKS; ++ks) {
        bf16x8 a = (bf16x8){0, 0, 0, 0, 0, 0, 0, 0};
        if (aok) a = *(const bf16x8*)(xr + ks * 32);
#pragma unroll
        for (int f = 0; f < NF; ++f) {
            size_t fb = (((size_t)ks * NF + f) * 64 + lane) * 8;
            bf16x8 bhi = *(const bf16x8*)(wpk + fb);
            bf16x8 blo = *(const bf16x8*)(wlo + fb);
            acc[f] = __builtin_amdgcn_mfma_f32_16x16x32_bf16(a, bhi, acc[f], 0, 0, 0);
            acc[f] = __builtin_amdgcn_mfma_f32_16x16x32_bf16(a, blo, acc[f], 0, 0, 0);
        }
    }

    int r0  = rowbase + (lane >> 4) * 4;
    int col = lane & 15;
#pragma unroll
    for (int f = 0; f < NF; ++f) {
#pragma unroll
        for (int i = 0; i < 4; ++i) {
            int r = r0 + i;
            if (r < n) Y[(size_t)r * ODIM + f * 16 + col] = f2bf(acc[f][i]);
        }
    }
}

// ---------------------------------------------------------------------------
// Gather F=128 (bf16 in, bf16 out): h1 = relu(selfloop + sum coef*xw + b1)
// One wave per node; 8-deep unroll.
// ---------------------------------------------------------------------------
__global__ void k_gather1(const unsigned short* __restrict__ xw, const int* __restrict__ rowptr,
                          const int2* __restrict__ csr,
                          const float* __restrict__ dinv, const float* __restrict__ bias,
                          unsigned short* __restrict__ out, int n) {
    int wave = threadIdx.x >> 6;
    int lane = threadIdx.x & 63;
    int i = blockIdx.x * 4 + wave;
    if (i >= n) return;

    float dv = dinv[i];
    float sl = dv * dv;
    int e0 = __builtin_amdgcn_readfirstlane(rowptr[i]);
    int e1 = __builtin_amdgcn_readfirstlane(rowptr[i + 1]);

    const unsigned int* base = (const unsigned int*)xw;  // row stride 64 u32
    unsigned int su = base[(size_t)i * 64 + lane];
    float ax0 = bf2f((unsigned short)(su & 0xffff)) * sl;
    float ay0 = bf2f((unsigned short)(su >> 16)) * sl;
    float ax1 = 0.f, ay1 = 0.f, ax2 = 0.f, ay2 = 0.f, ax3 = 0.f, ay3 = 0.f;
    int e = e0;
    for (; e + 8 <= e1; e += 8) {
        int2 p0 = csr[e + 0], p1 = csr[e + 1], p2 = csr[e + 2], p3 = csr[e + 3];
        int2 p4 = csr[e + 4], p5 = csr[e + 5], p6 = csr[e + 6], p7 = csr[e + 7];
        unsigned int u0 = base[(size_t)p0.x * 64 + lane];
        unsigned int u1 = base[(size_t)p1.x * 64 + lane];
        unsigned int u2 = base[(size_t)p2.x * 64 + lane];
        unsigned int u3 = base[(size_t)p3.x * 64 + lane];
        unsigned int u4 = base[(size_t)p4.x * 64 + lane];
        unsigned int u5 = base[(size_t)p5.x * 64 + lane];
        unsigned int u6 = base[(size_t)p6.x * 64 + lane];
        unsigned int u7 = base[(size_t)p7.x * 64 + lane];
        float c0 = __int_as_float(p0.y), c1 = __int_as_float(p1.y);
        float c2 = __int_as_float(p2.y), c3 = __int_as_float(p3.y);
        float c4 = __int_as_float(p4.y), c5 = __int_as_float(p5.y);
        float c6 = __int_as_float(p6.y), c7 = __int_as_float(p7.y);
        ax0 += c0 * bf2f((unsigned short)(u0 & 0xffff)); ay0 += c0 * bf2f((unsigned short)(u0 >> 16));
        ax1 += c1 * bf2f((unsigned short)(u1 & 0xffff)); ay1 += c1 * bf2f((unsigned short)(u1 >> 16));
        ax2 += c2 * bf2f((unsigned short)(u2 & 0xffff)); ay2 += c2 * bf2f((unsigned short)(u2 >> 16));
        ax3 += c3 * bf2f((unsigned short)(u3 & 0xffff)); ay3 += c3 * bf2f((unsigned short)(u3 >> 16));
        ax0 += c4 * bf2f((unsigned short)(u4 & 0xffff)); ay0 += c4 * bf2f((unsigned short)(u4 >> 16));
        ax1 += c5 * bf2f((unsigned short)(u5 & 0xffff)); ay1 += c5 * bf2f((unsigned short)(u5 >> 16));
        ax2 += c6 * bf2f((unsigned short)(u6 & 0xffff)); ay2 += c6 * bf2f((unsigned short)(u6 >> 16));
        ax3 += c7 * bf2f((unsigned short)(u7 & 0xffff)); ay3 += c7 * bf2f((unsigned short)(u7 >> 16));
    }
    for (; e + 2 <= e1; e += 2) {
        int2 p0 = csr[e + 0], p1 = csr[e + 1];
        unsigned int u0 = base[(size_t)p0.x * 64 + lane];
        unsigned int u1 = base[(size_t)p1.x * 64 + lane];
        float c0 = __int_as_float(p0.y), c1 = __int_as_float(p1.y);
        ax0 += c0 * bf2f((unsigned short)(u0 & 0xffff)); ay0 += c0 * bf2f((unsigned short)(u0 >> 16));
        ax1 += c1 * bf2f((unsigned short)(u1 & 0xffff)); ay1 += c1 * bf2f((unsigned short)(u1 >> 16));
    }
    if (e < e1) {
        int2 p0 = csr[e];
        unsigned int u0 = base[(size_t)p0.x * 64 + lane];
        float c0 = __int_as_float(p0.y);
        ax0 += c0 * bf2f((unsigned short)(u0 & 0xffff)); ay0 += c0 * bf2f((unsigned short)(u0 >> 16));
    }
    float2 bb = *((const float2*)bias + lane);
    float rx = fmaxf((ax0 + ax1) + (ax2 + ax3) + bb.x, 0.f);
    float ry = fmaxf((ay0 + ay1) + (ay2 + ay3) + bb.y, 0.f);
    unsigned int packed = (unsigned int)f2bf(rx) | ((unsigned int)f2bf(ry) << 16);
    ((unsigned int*)(out + (size_t)i * 128))[lane] = packed;
}

// ---------------------------------------------------------------------------
// Gather F=64 (bf16 in, f32 out): h2 = relu(selfloop + sum coef*xw2 + b2)
// ---------------------------------------------------------------------------
__global__ void k_gather2(const unsigned short* __restrict__ xw, const int* __restrict__ rowptr,
                          const int2* __restrict__ csr,
                          const float* __restrict__ dinv, const float* __restrict__ bias,
                          float* __restrict__ out, int n) {
    int wave = threadIdx.x >> 6;
    int lane = threadIdx.x & 63;
    int i = blockIdx.x * 4 + wave;
    if (i >= n) return;

    float dv = dinv[i];
    float sl = dv * dv;
    int e0 = __builtin_amdgcn_readfirstlane(rowptr[i]);
    int e1 = __builtin_amdgcn_readfirstlane(rowptr[i + 1]);

    float a0 = bf2f(xw[(size_t)i * 64 + lane]) * sl;
    float a1 = 0.f, a2 = 0.f, a3 = 0.f;
    int e = e0;
    for (; e + 8 <= e1; e += 8) {
        int2 p0 = csr[e + 0], p1 = csr[e + 1], p2 = csr[e + 2], p3 = csr[e + 3];
        int2 p4 = csr[e + 4], p5 = csr[e + 5], p6 = csr[e + 6], p7 = csr[e + 7];
        float v0 = bf2f(xw[(size_t)p0.x * 64 + lane]);
        float v1 = bf2f(xw[(size_t)p1.x * 64 + lane]);
        float v2 = bf2f(xw[(size_t)p2.x * 64 + lane]);
        float v3 = bf2f(xw[(size_t)p3.x * 64 + lane]);
        float v4 = bf2f(xw[(size_t)p4.x * 64 + lane]);
        float v5 = bf2f(xw[(size_t)p5.x * 64 + lane]);
        float v6 = bf2f(xw[(size_t)p6.x * 64 + lane]);
        float v7 = bf2f(xw[(size_t)p7.x * 64 + lane]);
        a0 += __int_as_float(p0.y) * v0; a1 += __int_as_float(p1.y) * v1;
        a2 += __int_as_float(p2.y) * v2; a3 += __int_as_float(p3.y) * v3;
        a0 += __int_as_float(p4.y) * v4; a1 += __int_as_float(p5.y) * v5;
        a2 += __int_as_float(p6.y) * v6; a3 += __int_as_float(p7.y) * v7;
    }
    for (; e + 2 <= e1; e += 2) {
        int2 p0 = csr[e + 0], p1 = csr[e + 1];
        a0 += __int_as_float(p0.y) * bf2f(xw[(size_t)p0.x * 64 + lane]);
        a1 += __int_as_float(p1.y) * bf2f(xw[(size_t)p1.x * 64 + lane]);
    }
    if (e < e1) {
        int2 p0 = csr[e];
        a0 += __int_as_float(p0.y) * bf2f(xw[(size_t)p0.x * 64 + lane]);
    }
    float res = fmaxf((a0 + a1) + (a2 + a3) + bias[lane], 0.f);
    out[(size_t)i * 64 + lane] = res;
}

// ---------------------------------------------------------------------------
// Two-stage mean-pool + head.
// ---------------------------------------------------------------------------
__global__ void k_fill(float* __restrict__ p, int n, float v) {
    int i = blockIdx.x * blockDim.x + threadIdx.x;
    if (i < n) p[i] = v;
}

__global__ void k_pool1(const float* __restrict__ h2, const int* __restrict__ batch,
                        float* __restrict__ sums, int n) {
    int b = blockIdx.x, t = threadIdx.x;
    int chunk = (n + gridDim.x - 1) / gridDim.x;
    int lo = b * chunk, hi = min(lo + chunk, n);
    if (lo >= hi) return;
    int f = t & 63, rg = t >> 6;  // 4 row-groups
    float acc = 0.f;
    int cur = -1;
    for (int r = lo + rg; r < hi; r += 4) {
        int g = batch[r];
        if (g != cur) {
            if (cur >= 0) atomicAdd(&sums[cur * 64 + f], acc);
            acc = 0.f;
            cur = g;
        }
        acc += h2[(size_t)r * 64 + f];
    }
    if (cur >= 0) atomicAdd(&sums[cur * 64 + f], acc);
}

__global__ void k_head(const float* __restrict__ sums, const int* __restrict__ batch,
                       const float* __restrict__ Wfc, const float* __restrict__ bfc,
                       float* __restrict__ out, int n) {
    int g = blockIdx.x;
    int f = threadIdx.x;  // 64 threads = 1 wave
    int lo0 = 0, hi0 = n;
    while (lo0 < hi0) { int m = (lo0 + hi0) >> 1; if (batch[m] < g) lo0 = m + 1; else hi0 = m; }
    int lo1 = lo0, hi1 = n;
    while (lo1 < hi1) { int m = (lo1 + hi1) >> 1; if (batch[m] < g + 1) lo1 = m + 1; else hi1 = m; }
    float cnt = (float)(lo1 - lo0);
    float v = sums[g * 64 + f] * Wfc[f];
#pragma unroll
    for (int o = 32; o > 0; o >>= 1) v += __shfl_down(v, o);
    if (f == 0) out[g] = v / fmaxf(cnt, 1.0f) + bfc[0];
}

extern "C" void kernel_launch(void* const* d_in, const int* in_sizes, int n_in,
                              void* d_out, int out_size, void* d_ws, size_t ws_size,
                              hipStream_t stream) {
    const float* x    = (const float*)d_in[0];
    const int*   ei   = (const int*)d_in[1];
    const float* ew   = (const float*)d_in[2];
    const int*   bat  = (const int*)d_in[3];
    const float* W1   = (const float*)d_in[4];
    const float* b1   = (const float*)d_in[5];
    const float* W2   = (const float*)d_in[6];
    const float* b2   = (const float*)d_in[7];
    const float* Wfc  = (const float*)d_in[8];
    const float* bfc  = (const float*)d_in[9];
    float*       out  = (float*)d_out;

    const int N = in_sizes[0] / 256;
    const int E = in_sizes[2];
    const int G = out_size;

    const int* src = ei;
    const int* dst = ei + E;

    const int NB_SCAN = (N + SC_CHUNK - 1) / SC_CHUNK;

    // workspace layout (8B-aligned chunks)
    const int Npad = (N + 4) & ~3;
    unsigned long long* pk     = (unsigned long long*)d_ws;          // N u64
    float*              dinv   = (float*)(pk + Npad);                // N
    int*                count  = (int*)(dinv + Npad);                // N
    int*                rowptr = count + Npad;                       // N+1
    int*                bsum   = rowptr + Npad;                      // NB_SCAN
    int*                slot   = bsum + ((NB_SCAN + 4) & ~3);        // E
    int2*               csr    = (int2*)(slot + ((E + 4) & ~3));    // E int2
    unsigned short*     wpk1   = (unsigned short*)(csr + E);        // 2*256*128
    unsigned short*     wpk2   = wpk1 + 2 * 256 * 128;               // 2*128*64
    float*              sums   = (float*)(wpk2 + 2 * 128 * 64);     // G*64
    unsigned short*     bufA   = (unsigned short*)(sums + ((G * 64 + 4) & ~3)); // N*128 bf16: xw1, later xw2
    unsigned short*     bufH1  = bufA + (size_t)N * 128;             // N*128 bf16: h1
    float*              bufH2  = (float*)(bufH1 + (size_t)N * 128); // N*64 f32: h2

    const int B = 256;

    // 1) init + weight pre-pack (all independent, tiny)
    k_init_pk<<<ceil_div_ll(N, B), B, 0, stream>>>(pk, N);
    k_wpack<256, 128><<<(8 * 8 * 64 + B - 1) / B, B, 0, stream>>>(W1, wpk1);
    k_wpack<128, 64><<<(4 * 4 * 64 + B - 1) / B, B, 0, stream>>>(W2, wpk2);

    // 2) fused: deg/count atomics (needs init_pk) || gemm1 (needs wpack1)
    {
        int degBlocks  = ceil_div_ll(E, B);
        int gemmBlocks = ceil_div_ll(N, 64);
        int total      = degBlocks + gemmBlocks;
        int stride     = total / gemmBlocks;  // every stride-th block is gemm
        if (stride < 1) stride = 1;
        k_deg_gemm1<<<total, B, 0, stream>>>(dst, ew, pk, slot, E,
                                             x, wpk1, bufA, N, gemmBlocks, stride);
    }
    k_finish<<<ceil_div_ll(N, B), B, 0, stream>>>(pk, dinv, count, N);

    // 3) CSR build: parallel scan + atomic-free fill
    k_scan_a<<<NB_SCAN, SC_T, 0, stream>>>(count, bsum, N);
    k_scan_b<<<1, 64, 0, stream>>>(bsum, NB_SCAN);
    k_scan_c<<<NB_SCAN, SC_T, 0, stream>>>(count, rowptr, bsum, N);
    k_csr_fill<<<ceil_div_ll(E, B), B, 0, stream>>>(src, dst, ew, dinv, rowptr,
                                                    slot, csr, E);

    // 4) layer 1 gather: h1(bf16) = relu(gather(xw1) + b1)
    k_gather1<<<ceil_div_ll(N, 4), 256, 0, stream>>>(
        bufA, rowptr, csr, dinv, b1, bufH1, N);

    // 5) layer 2: xw2(bf16) = h1(bf16) @ W2 ; h2(f32) = relu(gather + b2)
    k_gemm_mfma_bfA<128, 64><<<ceil_div_ll(N, 64), 256, 0, stream>>>(bufH1, wpk2, bufA, N);
    k_gather2<<<ceil_div_ll(N, 4), 256, 0, stream>>>(
        bufA, rowptr, csr, dinv, b2, bufH2, N);

    // 6) two-stage mean-pool + head
    k_fill<<<ceil_div_ll(G * 64, B), B, 0, stream>>>(sums, G * 64, 0.0f);
    k_pool1<<<1024, 256, 0, stream>>>(bufH2, bat, sums, N);
    k_head<<<G, 64, 0, stream>>>(sums, bat, Wfc, bfc, out, N);
}

// Round 11
// 350.340 us; speedup vs baseline: 1.1675x; 1.1675x over previous
//
#include <hip/hip_runtime.h>
#include <hip/hip_bf16.h>

// ---------------------------------------------------------------------------
// RewardGNN: 2-layer GCN (256->128->64) + mean-pool + linear head.
// Round 11: revert round-10 fusion (64-VGPR fused kernel cut the atomic
//   phase's occupancy 66%->19% -> 3x slower). Keep h1-bf16. New:
//   k_deg_count processes 4 edges/thread (4 independent u64 atomics in
//   flight -> 4x MLP for the latency-bound atomic phase).
// ---------------------------------------------------------------------------

static inline int ceil_div_ll(long long a, int b) { return (int)((a + b - 1) / b); }

typedef __attribute__((ext_vector_type(8))) short bf16x8;
typedef __attribute__((ext_vector_type(4))) float f32x4;

#define FIX_SCALE 33554432.0f   // 2^25

__device__ inline unsigned short f2bf(float f) {
    __hip_bfloat16 h = __float2bfloat16(f);  // round-to-nearest-even
    return *reinterpret_cast<unsigned short*>(&h);
}
__device__ inline float bf2f(unsigned short u) {
    unsigned int x = ((unsigned int)u) << 16;
    return __uint_as_float(x);
}

// pk[i] = count<<32 | deg_fixed ; init deg=1.0 (self-loop), count=0
__global__ void k_init_pk(unsigned long long* __restrict__ pk, int n) {
    int i = blockIdx.x * blockDim.x + threadIdx.x;
    if (i < n) pk[i] = (unsigned long long)(1u << 25);
}

// 4 edges per thread: 4 independent u64 atomics in flight (latency-bound phase)
__global__ void k_deg_count(const int* __restrict__ dst, const float* __restrict__ ew,
                            unsigned long long* __restrict__ pk, int* __restrict__ slot, int E) {
    int t = blockIdx.x * blockDim.x + threadIdx.x;
    int e = t * 4;
    if (e + 4 <= E) {
        int4   d4 = *(const int4*)(dst + e);
        float4 w4 = *(const float4*)(ew + e);
        unsigned long long o0 = atomicAdd(&pk[d4.x],
            (1ull << 32) | (unsigned long long)__float2uint_rn(w4.x * FIX_SCALE));
        unsigned long long o1 = atomicAdd(&pk[d4.y],
            (1ull << 32) | (unsigned long long)__float2uint_rn(w4.y * FIX_SCALE));
        unsigned long long o2 = atomicAdd(&pk[d4.z],
            (1ull << 32) | (unsigned long long)__float2uint_rn(w4.z * FIX_SCALE));
        unsigned long long o3 = atomicAdd(&pk[d4.w],
            (1ull << 32) | (unsigned long long)__float2uint_rn(w4.w * FIX_SCALE));
        *(int4*)(slot + e) = make_int4((int)(o0 >> 32), (int)(o1 >> 32),
                                       (int)(o2 >> 32), (int)(o3 >> 32));
    } else if (e < E) {
        for (int k = e; k < E; ++k) {
            unsigned int fx = __float2uint_rn(ew[k] * FIX_SCALE);
            unsigned long long old =
                atomicAdd(&pk[dst[k]], (1ull << 32) | (unsigned long long)fx);
            slot[k] = (int)(old >> 32);
        }
    }
}

// dinv[i] = rsqrt(deg), count[i] = in-count
__global__ void k_finish(const unsigned long long* __restrict__ pk, float* __restrict__ dinv,
                         int* __restrict__ count, int n) {
    int i = blockIdx.x * blockDim.x + threadIdx.x;
    if (i < n) {
        unsigned long long v = pk[i];
        float deg = (float)(unsigned int)(v & 0xffffffffull) * (1.0f / FIX_SCALE);
        dinv[i] = (deg > 0.f) ? rsqrtf(deg) : 0.f;
        count[i] = (int)(v >> 32);
    }
}

// ------------------------- 3-phase parallel scan ---------------------------
constexpr int SC_T = 256;
constexpr int SC_PER = 16;
constexpr int SC_CHUNK = SC_T * SC_PER;

__global__ void k_scan_a(const int* __restrict__ count, int* __restrict__ bsum, int n) {
    __shared__ int lds[SC_T];
    int b = blockIdx.x, t = threadIdx.x;
    int base = b * SC_CHUNK + t * SC_PER;
    int s = 0;
#pragma unroll
    for (int k = 0; k < SC_PER; ++k) {
        int idx = base + k;
        if (idx < n) s += count[idx];
    }
    lds[t] = s;
    __syncthreads();
    for (int off = 128; off > 0; off >>= 1) {
        if (t < off) lds[t] += lds[t + off];
        __syncthreads();
    }
    if (t == 0) bsum[b] = lds[0];
}

__global__ void k_scan_b(int* __restrict__ bsum, int nb) {
    if (threadIdx.x == 0) {
        int run = 0;
        for (int i = 0; i < nb; ++i) { int c = bsum[i]; bsum[i] = run; run += c; }
    }
}

__global__ void k_scan_c(const int* __restrict__ count, int* __restrict__ rowptr,
                         const int* __restrict__ bsum, int n) {
    __shared__ int lds[SC_T];
    int b = blockIdx.x, t = threadIdx.x;
    int base = b * SC_CHUNK + t * SC_PER;
    int v[SC_PER];
    int s = 0;
#pragma unroll
    for (int k = 0; k < SC_PER; ++k) {
        int idx = base + k;
        v[k] = (idx < n) ? count[idx] : 0;
        s += v[k];
    }
    lds[t] = s;
    for (int off = 1; off < SC_T; off <<= 1) {
        __syncthreads();
        int tmp = (t >= off) ? lds[t - off] : 0;
        __syncthreads();
        lds[t] += tmp;
    }
    __syncthreads();
    int run = bsum[b] + lds[t] - s;
#pragma unroll
    for (int k = 0; k < SC_PER; ++k) {
        int idx = base + k;
        if (idx < n) {
            rowptr[idx] = run;
            run += v[k];
            if (idx == n - 1) rowptr[n] = run;
        }
    }
}

// Fill CSR without atomics: pos = rowptr[dst] + slot[e]; one int2 store.
__global__ void k_csr_fill(const int* __restrict__ src, const int* __restrict__ dst,
                           const float* __restrict__ ew, const float* __restrict__ dinv,
                           const int* __restrict__ rowptr, const int* __restrict__ slot,
                           int2* __restrict__ csr, int E) {
    int e = blockIdx.x * blockDim.x + threadIdx.x;
    if (e < E) {
        int s = src[e], d = dst[e];
        int pos = rowptr[d] + slot[e];
        float coef = dinv[s] * ew[e] * dinv[d];
        csr[pos] = make_int2(s, __float_as_int(coef));
    }
}

// ---------------------------------------------------------------------------
// W pre-pack into MFMA B-fragment layout (hi/lo bf16).
// ---------------------------------------------------------------------------
template <int KDIM, int ODIM>
__global__ void k_wpack(const float* __restrict__ W, unsigned short* __restrict__ wpk) {
    constexpr int NKS = KDIM / 32, NF = ODIM / 16;
    int t = blockIdx.x * blockDim.x + threadIdx.x;
    if (t >= NKS * NF * 64) return;
    int lane = t & 63;
    int nf   = (t >> 6) % NF;
    int ks   = t / (64 * NF);
    int col  = nf * 16 + (lane & 15);
    int kb   = ks * 32 + (lane >> 4) * 8;
    bf16x8 hi, lo;
#pragma unroll
    for (int i = 0; i < 8; ++i) {
        float w = W[(size_t)(kb + i) * ODIM + col];
        unsigned short h = f2bf(w);
        hi[i] = (short)h;
        lo[i] = (short)f2bf(w - bf2f(h));
    }
    size_t base = (size_t)t * 8;
    *(bf16x8*)(wpk + base) = hi;
    *(bf16x8*)(wpk + (size_t)KDIM * ODIM + base) = lo;
}

// ---------------------------------------------------------------------------
// GEMM1: f32 A, split-precision (3 mfma), bf16 out.
// ---------------------------------------------------------------------------
template <int KDIM, int ODIM>
__global__ void k_gemm_mfma(const float* __restrict__ X,
                            const unsigned short* __restrict__ wpk,
                            unsigned short* __restrict__ Y, int n) {
    constexpr int NKS = KDIM / 32, NF = ODIM / 16;
    int wid  = threadIdx.x >> 6;
    int lane = threadIdx.x & 63;
    int rowbase = blockIdx.x * 64 + wid * 16;
    int arow = rowbase + (lane & 15);
    int kb0  = (lane >> 4) * 8;
    const unsigned short* wlo = wpk + (size_t)KDIM * ODIM;
    bool aok = (arow < n);
    const float* xr = X + (size_t)arow * KDIM + kb0;

    f32x4 acc[NF];
#pragma unroll
    for (int f = 0; f < NF; ++f) acc[f] = (f32x4){0.f, 0.f, 0.f, 0.f};

#pragma unroll
    for (int ks = 0; ks < NKS; ++ks) {
        f32x4 a0 = (f32x4){0.f, 0.f, 0.f, 0.f};
        f32x4 a1 = (f32x4){0.f, 0.f, 0.f, 0.f};
        if (aok) {
            a0 = *(const f32x4*)(xr + ks * 32);
            a1 = *(const f32x4*)(xr + ks * 32 + 4);
        }
        bf16x8 ahi, alo;
#pragma unroll
        for (int i = 0; i < 4; ++i) {
            unsigned short h0 = f2bf(a0[i]);
            ahi[i]     = (short)h0;
            alo[i]     = (short)f2bf(a0[i] - bf2f(h0));
            unsigned short h1 = f2bf(a1[i]);
            ahi[i + 4] = (short)h1;
            alo[i + 4] = (short)f2bf(a1[i] - bf2f(h1));
        }
#pragma unroll
        for (int f = 0; f < NF; ++f) {
            size_t fb = (((size_t)ks * NF + f) * 64 + lane) * 8;
            bf16x8 bhi = *(const bf16x8*)(wpk + fb);
            bf16x8 blo = *(const bf16x8*)(wlo + fb);
            acc[f] = __builtin_amdgcn_mfma_f32_16x16x32_bf16(ahi, bhi, acc[f], 0, 0, 0);
            acc[f] = __builtin_amdgcn_mfma_f32_16x16x32_bf16(alo, bhi, acc[f], 0, 0, 0);
            acc[f] = __builtin_amdgcn_mfma_f32_16x16x32_bf16(ahi, blo, acc[f], 0, 0, 0);
        }
    }

    int r0  = rowbase + (lane >> 4) * 4;
    int col = lane & 15;
#pragma unroll
    for (int f = 0; f < NF; ++f) {
#pragma unroll
        for (int i = 0; i < 4; ++i) {
            int r = r0 + i;
            if (r < n) Y[(size_t)r * ODIM + f * 16 + col] = f2bf(acc[f][i]);
        }
    }
}

// ---------------------------------------------------------------------------
// GEMM2: bf16 A (h1 stored bf16 -> exact fragment, no split), B hi/lo (2 mfma).
// ---------------------------------------------------------------------------
template <int KDIM, int ODIM>
__global__ void k_gemm_mfma_bfA(const unsigned short* __restrict__ X,
                                const unsigned short* __restrict__ wpk,
                                unsigned short* __restrict__ Y, int n) {
    constexpr int NKS = KDIM / 32, NF = ODIM / 16;
    int wid  = threadIdx.x >> 6;
    int lane = threadIdx.x & 63;
    int rowbase = blockIdx.x * 64 + wid * 16;
    int arow = rowbase + (lane & 15);
    int kb0  = (lane >> 4) * 8;
    const unsigned short* wlo = wpk + (size_t)KDIM * ODIM;
    bool aok = (arow < n);
    const unsigned short* xr = X + (size_t)arow * KDIM + kb0;

    f32x4 acc[NF];
#pragma unroll
    for (int f = 0; f < NF; ++f) acc[f] = (f32x4){0.f, 0.f, 0.f, 0.f};

#pragma unroll
    for (int ks = 0; ks < NKS; ++ks) {
        bf16x8 a = (bf16x8){0, 0, 0, 0, 0, 0, 0, 0};
        if (aok) a = *(const bf16x8*)(xr + ks * 32);
#pragma unroll
        for (int f = 0; f < NF; ++f) {
            size_t fb = (((size_t)ks * NF + f) * 64 + lane) * 8;
            bf16x8 bhi = *(const bf16x8*)(wpk + fb);
            bf16x8 blo = *(const bf16x8*)(wlo + fb);
            acc[f] = __builtin_amdgcn_mfma_f32_16x16x32_bf16(a, bhi, acc[f], 0, 0, 0);
            acc[f] = __builtin_amdgcn_mfma_f32_16x16x32_bf16(a, blo, acc[f], 0, 0, 0);
        }
    }

    int r0  = rowbase + (lane >> 4) * 4;
    int col = lane & 15;
#pragma unroll
    for (int f = 0; f < NF; ++f) {
#pragma unroll
        for (int i = 0; i < 4; ++i) {
            int r = r0 + i;
            if (r < n) Y[(size_t)r * ODIM + f * 16 + col] = f2bf(acc[f][i]);
        }
    }
}

// ---------------------------------------------------------------------------
// Gather F=128 (bf16 in, bf16 out): h1 = relu(selfloop + sum coef*xw + b1)
// One wave per node; 8-deep unroll.
// ---------------------------------------------------------------------------
__global__ void k_gather1(const unsigned short* __restrict__ xw, const int* __restrict__ rowptr,
                          const int2* __restrict__ csr,
                          const float* __restrict__ dinv, const float* __restrict__ bias,
                          unsigned short* __restrict__ out, int n) {
    int wave = threadIdx.x >> 6;
    int lane = threadIdx.x & 63;
    int i = blockIdx.x * 4 + wave;
    if (i >= n) return;

    float dv = dinv[i];
    float sl = dv * dv;
    int e0 = __builtin_amdgcn_readfirstlane(rowptr[i]);
    int e1 = __builtin_amdgcn_readfirstlane(rowptr[i + 1]);

    const unsigned int* base = (const unsigned int*)xw;  // row stride 64 u32
    unsigned int su = base[(size_t)i * 64 + lane];
    float ax0 = bf2f((unsigned short)(su & 0xffff)) * sl;
    float ay0 = bf2f((unsigned short)(su >> 16)) * sl;
    float ax1 = 0.f, ay1 = 0.f, ax2 = 0.f, ay2 = 0.f, ax3 = 0.f, ay3 = 0.f;
    int e = e0;
    for (; e + 8 <= e1; e += 8) {
        int2 p0 = csr[e + 0], p1 = csr[e + 1], p2 = csr[e + 2], p3 = csr[e + 3];
        int2 p4 = csr[e + 4], p5 = csr[e + 5], p6 = csr[e + 6], p7 = csr[e + 7];
        unsigned int u0 = base[(size_t)p0.x * 64 + lane];
        unsigned int u1 = base[(size_t)p1.x * 64 + lane];
        unsigned int u2 = base[(size_t)p2.x * 64 + lane];
        unsigned int u3 = base[(size_t)p3.x * 64 + lane];
        unsigned int u4 = base[(size_t)p4.x * 64 + lane];
        unsigned int u5 = base[(size_t)p5.x * 64 + lane];
        unsigned int u6 = base[(size_t)p6.x * 64 + lane];
        unsigned int u7 = base[(size_t)p7.x * 64 + lane];
        float c0 = __int_as_float(p0.y), c1 = __int_as_float(p1.y);
        float c2 = __int_as_float(p2.y), c3 = __int_as_float(p3.y);
        float c4 = __int_as_float(p4.y), c5 = __int_as_float(p5.y);
        float c6 = __int_as_float(p6.y), c7 = __int_as_float(p7.y);
        ax0 += c0 * bf2f((unsigned short)(u0 & 0xffff)); ay0 += c0 * bf2f((unsigned short)(u0 >> 16));
        ax1 += c1 * bf2f((unsigned short)(u1 & 0xffff)); ay1 += c1 * bf2f((unsigned short)(u1 >> 16));
        ax2 += c2 * bf2f((unsigned short)(u2 & 0xffff)); ay2 += c2 * bf2f((unsigned short)(u2 >> 16));
        ax3 += c3 * bf2f((unsigned short)(u3 & 0xffff)); ay3 += c3 * bf2f((unsigned short)(u3 >> 16));
        ax0 += c4 * bf2f((unsigned short)(u4 & 0xffff)); ay0 += c4 * bf2f((unsigned short)(u4 >> 16));
        ax1 += c5 * bf2f((unsigned short)(u5 & 0xffff)); ay1 += c5 * bf2f((unsigned short)(u5 >> 16));
        ax2 += c6 * bf2f((unsigned short)(u6 & 0xffff)); ay2 += c6 * bf2f((unsigned short)(u6 >> 16));
        ax3 += c7 * bf2f((unsigned short)(u7 & 0xffff)); ay3 += c7 * bf2f((unsigned short)(u7 >> 16));
    }
    for (; e + 2 <= e1; e += 2) {
        int2 p0 = csr[e + 0], p1 = csr[e + 1];
        unsigned int u0 = base[(size_t)p0.x * 64 + lane];
        unsigned int u1 = base[(size_t)p1.x * 64 + lane];
        float c0 = __int_as_float(p0.y), c1 = __int_as_float(p1.y);
        ax0 += c0 * bf2f((unsigned short)(u0 & 0xffff)); ay0 += c0 * bf2f((unsigned short)(u0 >> 16));
        ax1 += c1 * bf2f((unsigned short)(u1 & 0xffff)); ay1 += c1 * bf2f((unsigned short)(u1 >> 16));
    }
    if (e < e1) {
        int2 p0 = csr[e];
        unsigned int u0 = base[(size_t)p0.x * 64 + lane];
        float c0 = __int_as_float(p0.y);
        ax0 += c0 * bf2f((unsigned short)(u0 & 0xffff)); ay0 += c0 * bf2f((unsigned short)(u0 >> 16));
    }
    float2 bb = *((const float2*)bias + lane);
    float rx = fmaxf((ax0 + ax1) + (ax2 + ax3) + bb.x, 0.f);
    float ry = fmaxf((ay0 + ay1) + (ay2 + ay3) + bb.y, 0.f);
    unsigned int packed = (unsigned int)f2bf(rx) | ((unsigned int)f2bf(ry) << 16);
    ((unsigned int*)(out + (size_t)i * 128))[lane] = packed;
}

// ---------------------------------------------------------------------------
// Gather F=64 (bf16 in, f32 out): h2 = relu(selfloop + sum coef*xw2 + b2)
// ---------------------------------------------------------------------------
__global__ void k_gather2(const unsigned short* __restrict__ xw, const int* __restrict__ rowptr,
                          const int2* __restrict__ csr,
                          const float* __restrict__ dinv, const float* __restrict__ bias,
                          float* __restrict__ out, int n) {
    int wave = threadIdx.x >> 6;
    int lane = threadIdx.x & 63;
    int i = blockIdx.x * 4 + wave;
    if (i >= n) return;

    float dv = dinv[i];
    float sl = dv * dv;
    int e0 = __builtin_amdgcn_readfirstlane(rowptr[i]);
    int e1 = __builtin_amdgcn_readfirstlane(rowptr[i + 1]);

    float a0 = bf2f(xw[(size_t)i * 64 + lane]) * sl;
    float a1 = 0.f, a2 = 0.f, a3 = 0.f;
    int e = e0;
    for (; e + 8 <= e1; e += 8) {
        int2 p0 = csr[e + 0], p1 = csr[e + 1], p2 = csr[e + 2], p3 = csr[e + 3];
        int2 p4 = csr[e + 4], p5 = csr[e + 5], p6 = csr[e + 6], p7 = csr[e + 7];
        float v0 = bf2f(xw[(size_t)p0.x * 64 + lane]);
        float v1 = bf2f(xw[(size_t)p1.x * 64 + lane]);
        float v2 = bf2f(xw[(size_t)p2.x * 64 + lane]);
        float v3 = bf2f(xw[(size_t)p3.x * 64 + lane]);
        float v4 = bf2f(xw[(size_t)p4.x * 64 + lane]);
        float v5 = bf2f(xw[(size_t)p5.x * 64 + lane]);
        float v6 = bf2f(xw[(size_t)p6.x * 64 + lane]);
        float v7 = bf2f(xw[(size_t)p7.x * 64 + lane]);
        a0 += __int_as_float(p0.y) * v0; a1 += __int_as_float(p1.y) * v1;
        a2 += __int_as_float(p2.y) * v2; a3 += __int_as_float(p3.y) * v3;
        a0 += __int_as_float(p4.y) * v4; a1 += __int_as_float(p5.y) * v5;
        a2 += __int_as_float(p6.y) * v6; a3 += __int_as_float(p7.y) * v7;
    }
    for (; e + 2 <= e1; e += 2) {
        int2 p0 = csr[e + 0], p1 = csr[e + 1];
        a0 += __int_as_float(p0.y) * bf2f(xw[(size_t)p0.x * 64 + lane]);
        a1 += __int_as_float(p1.y) * bf2f(xw[(size_t)p1.x * 64 + lane]);
    }
    if (e < e1) {
        int2 p0 = csr[e];
        a0 += __int_as_float(p0.y) * bf2f(xw[(size_t)p0.x * 64 + lane]);
    }
    float res = fmaxf((a0 + a1) + (a2 + a3) + bias[lane], 0.f);
    out[(size_t)i * 64 + lane] = res;
}

// ---------------------------------------------------------------------------
// Two-stage mean-pool + head.
// ---------------------------------------------------------------------------
__global__ void k_fill(float* __restrict__ p, int n, float v) {
    int i = blockIdx.x * blockDim.x + threadIdx.x;
    if (i < n) p[i] = v;
}

__global__ void k_pool1(const float* __restrict__ h2, const int* __restrict__ batch,
                        float* __restrict__ sums, int n) {
    int b = blockIdx.x, t = threadIdx.x;
    int chunk = (n + gridDim.x - 1) / gridDim.x;
    int lo = b * chunk, hi = min(lo + chunk, n);
    if (lo >= hi) return;
    int f = t & 63, rg = t >> 6;  // 4 row-groups
    float acc = 0.f;
    int cur = -1;
    for (int r = lo + rg; r < hi; r += 4) {
        int g = batch[r];
        if (g != cur) {
            if (cur >= 0) atomicAdd(&sums[cur * 64 + f], acc);
            acc = 0.f;
            cur = g;
        }
        acc += h2[(size_t)r * 64 + f];
    }
    if (cur >= 0) atomicAdd(&sums[cur * 64 + f], acc);
}

__global__ void k_head(const float* __restrict__ sums, const int* __restrict__ batch,
                       const float* __restrict__ Wfc, const float* __restrict__ bfc,
                       float* __restrict__ out, int n) {
    int g = blockIdx.x;
    int f = threadIdx.x;  // 64 threads = 1 wave
    int lo0 = 0, hi0 = n;
    while (lo0 < hi0) { int m = (lo0 + hi0) >> 1; if (batch[m] < g) lo0 = m + 1; else hi0 = m; }
    int lo1 = lo0, hi1 = n;
    while (lo1 < hi1) { int m = (lo1 + hi1) >> 1; if (batch[m] < g + 1) lo1 = m + 1; else hi1 = m; }
    float cnt = (float)(lo1 - lo0);
    float v = sums[g * 64 + f] * Wfc[f];
#pragma unroll
    for (int o = 32; o > 0; o >>= 1) v += __shfl_down(v, o);
    if (f == 0) out[g] = v / fmaxf(cnt, 1.0f) + bfc[0];
}

extern "C" void kernel_launch(void* const* d_in, const int* in_sizes, int n_in,
                              void* d_out, int out_size, void* d_ws, size_t ws_size,
                              hipStream_t stream) {
    const float* x    = (const float*)d_in[0];
    const int*   ei   = (const int*)d_in[1];
    const float* ew   = (const float*)d_in[2];
    const int*   bat  = (const int*)d_in[3];
    const float* W1   = (const float*)d_in[4];
    const float* b1   = (const float*)d_in[5];
    const float* W2   = (const float*)d_in[6];
    const float* b2   = (const float*)d_in[7];
    const float* Wfc  = (const float*)d_in[8];
    const float* bfc  = (const float*)d_in[9];
    float*       out  = (float*)d_out;

    const int N = in_sizes[0] / 256;
    const int E = in_sizes[2];
    const int G = out_size;

    const int* src = ei;
    const int* dst = ei + E;

    const int NB_SCAN = (N + SC_CHUNK - 1) / SC_CHUNK;

    // workspace layout (8B-aligned chunks)
    const int Npad = (N + 4) & ~3;
    unsigned long long* pk     = (unsigned long long*)d_ws;          // N u64
    float*              dinv   = (float*)(pk + Npad);                // N
    int*                count  = (int*)(dinv + Npad);                // N
    int*                rowptr = count + Npad;                       // N+1
    int*                bsum   = rowptr + Npad;                      // NB_SCAN
    int*                slot   = bsum + ((NB_SCAN + 4) & ~3);        // E
    int2*               csr    = (int2*)(slot + ((E + 4) & ~3));    // E int2
    unsigned short*     wpk1   = (unsigned short*)(csr + E);        // 2*256*128
    unsigned short*     wpk2   = wpk1 + 2 * 256 * 128;               // 2*128*64
    float*              sums   = (float*)(wpk2 + 2 * 128 * 64);     // G*64
    unsigned short*     bufA   = (unsigned short*)(sums + ((G * 64 + 4) & ~3)); // N*128 bf16: xw1, later xw2
    unsigned short*     bufH1  = bufA + (size_t)N * 128;             // N*128 bf16: h1
    float*              bufH2  = (float*)(bufH1 + (size_t)N * 128); // N*64 f32: h2

    const int B = 256;

    // 1) packed degree + count (+ per-edge slot): 4 edges/thread for atomic MLP
    k_init_pk<<<ceil_div_ll(N, B), B, 0, stream>>>(pk, N);
    k_deg_count<<<ceil_div_ll((E + 3) / 4, B), B, 0, stream>>>(dst, ew, pk, slot, E);
    k_finish<<<ceil_div_ll(N, B), B, 0, stream>>>(pk, dinv, count, N);

    // 2) CSR build: parallel scan + atomic-free fill
    k_scan_a<<<NB_SCAN, SC_T, 0, stream>>>(count, bsum, N);
    k_scan_b<<<1, 64, 0, stream>>>(bsum, NB_SCAN);
    k_scan_c<<<NB_SCAN, SC_T, 0, stream>>>(count, rowptr, bsum, N);
    k_csr_fill<<<ceil_div_ll(E, B), B, 0, stream>>>(src, dst, ew, dinv, rowptr,
                                                    slot, csr, E);

    // W pre-pack
    k_wpack<256, 128><<<(8 * 8 * 64 + B - 1) / B, B, 0, stream>>>(W1, wpk1);
    k_wpack<128, 64><<<(4 * 4 * 64 + B - 1) / B, B, 0, stream>>>(W2, wpk2);

    // 3) layer 1: xw1(bf16) = x @ W1 ; h1(bf16) = relu(gather + b1)
    k_gemm_mfma<256, 128><<<ceil_div_ll(N, 64), 256, 0, stream>>>(x, wpk1, bufA, N);
    k_gather1<<<ceil_div_ll(N, 4), 256, 0, stream>>>(
        bufA, rowptr, csr, dinv, b1, bufH1, N);

    // 4) layer 2: xw2(bf16) = h1(bf16) @ W2 ; h2(f32) = relu(gather + b2)
    k_gemm_mfma_bfA<128, 64><<<ceil_div_ll(N, 64), 256, 0, stream>>>(bufH1, wpk2, bufA, N);
    k_gather2<<<ceil_div_ll(N, 4), 256, 0, stream>>>(
        bufA, rowptr, csr, dinv, b2, bufH2, N);

    // 5) two-stage mean-pool + head
    k_fill<<<ceil_div_ll(G * 64, B), B, 0, stream>>>(sums, G * 64, 0.0f);
    k_pool1<<<1024, 256, 0, stream>>>(bufH2, bat, sums, N);
    k_head<<<G, 64, 0, stream>>>(sums, bat, Wfc, bfc, out, N);
}